// Round 1
// 271.270 us; speedup vs baseline: 1.0303x; 1.0303x over previous
//
#include <hip/hip_runtime.h>

// InteractLayer via bf16 MFMA (16x16x32). B=16384 batches, F=32, D=64, H=64 (2 heads x 32).
// Pre-kernel: W (4x [64x64] f32) -> bf16 transposed Wt[e][d] in d_ws.
// Main: block = 1 batch, 4 waves. Phase1: wave w computes projection w (Q,K,V,R);
// V and R stored TRANSPOSED ([e][tok]) so C/D reg-index r is contiguous -> packed b64 LDS writes.
// Phase2: wave=(head,rowblock), QK^T + in-register softmax, P into s_xp (aliased over dead s_x).
// Phase3 (NO barrier: same-wave P rows, s_vt/s_rt covered by barrier 2): PV + residual + relu.
// All f32->bf16 via native (__bf16) cast -> v_cvt_pk_bf16_f32 (RNE, bit-identical to old f2bf).

constexpr int kF = 32, kD = 64, kH = 64;

constexpr int XS = 72;   // s_x row stride (bf16): 144B rows, 16B aligned
constexpr int QS = 72;   // s_q / s_k row stride
constexpr int VS = 40;   // s_vt / s_rt row stride (80B rows, 16B aligned)
constexpr int PS = 40;   // s_p row stride

using short8   = __attribute__((ext_vector_type(8))) short;
using float4v  = __attribute__((ext_vector_type(4))) float;
using ushort4v = __attribute__((ext_vector_type(4))) unsigned short;

__device__ __forceinline__ unsigned short f2bf(float x) {
    // native RNE convert (v_cvt_pk_bf16_f32) — 1 VALU op vs 4-op bit trick
    return __builtin_bit_cast(unsigned short, (__bf16)x);
}
__device__ __forceinline__ float bf2f(unsigned short b) {
    return __uint_as_float((unsigned)b << 16);
}

__global__ void wprep_kernel(const float* __restrict__ Wq, const float* __restrict__ Wk,
                             const float* __restrict__ Wv, const float* __restrict__ Wr,
                             unsigned short* __restrict__ wt) {
    const int m = blockIdx.x;               // 0..3 : Q,K,V,R
    const float* __restrict__ W = (m == 0) ? Wq : (m == 1) ? Wk : (m == 2) ? Wv : Wr;
    for (int i = threadIdx.x; i < kD * kH; i += blockDim.x) {
        const int e = i >> 6, d = i & 63;
        wt[m * kD * kH + e * kD + d] = f2bf(W[d * kH + e]);   // transposed: Wt[e][d]
    }
}

__global__ __launch_bounds__(256)
void interact_mfma(const float* __restrict__ X, const unsigned short* __restrict__ Wt,
                   float* __restrict__ out)
{
    // s_xp: X staging (kF*XS = 2304 elems) during phases 0-1, reused as P (2*kF*PS = 2560)
    // in phases 2-3. Total LDS = 24576 B -> 6 blocks/CU (was 28672 -> 5).
    __shared__ __align__(16) unsigned short s_xp[2 * kF * PS];
    __shared__ __align__(16) unsigned short s_q [kF * QS];
    __shared__ __align__(16) unsigned short s_k [kF * QS];
    __shared__ __align__(16) unsigned short s_vt[kH * VS];      // Vt[e][token]
    __shared__ __align__(16) unsigned short s_rt[kH * VS];      // Rt[e][token]

    const int t    = threadIdx.x;
    const int w    = t >> 6;        // wave 0..3
    const int lane = t & 63;
    const int quad = lane >> 4;     // 0..3
    const int l    = lane & 15;
    const int b    = blockIdx.x;

    // ---- W B-fragments for projection (wave w owns matrix w), from global Wt ----
    // B[k=d][n=e] frag: lane holds Wt[e = 16*nt + l][d = 32*ks + quad*8 + j]
    short8 bfrag[4][2];
    {
        const unsigned short* __restrict__ wtm = Wt + w * (kD * kH);
        #pragma unroll
        for (int nt = 0; nt < 4; ++nt)
            #pragma unroll
            for (int ks = 0; ks < 2; ++ks)
                bfrag[nt][ks] =
                    *reinterpret_cast<const short8*>(wtm + (16 * nt + l) * kD + 32 * ks + quad * 8);
    }

    // ---- stage X -> LDS (bf16) ----
    const float* __restrict__ Xb = X + (size_t)b * (kF * kD);
    #pragma unroll
    for (int i = 0; i < 2; ++i) {
        const int idx = i * 256 + t;          // 0..511 float4s
        const int f = idx >> 4, c = idx & 15;
        const float4 v = reinterpret_cast<const float4*>(Xb)[idx];
        ushort4v pk = { f2bf(v.x), f2bf(v.y), f2bf(v.z), f2bf(v.w) };
        *reinterpret_cast<ushort4v*>(&s_xp[f * XS + c * 4]) = pk;
    }
    __syncthreads();

    // ---- phase 1: projection w: Out[32x64] = X[32x64] @ W_w[64x64] ----
    {
        float4v acc[2][4];
        #pragma unroll
        for (int mt = 0; mt < 2; ++mt)
            #pragma unroll
            for (int nt = 0; nt < 4; ++nt)
                acc[mt][nt] = (float4v){0.f, 0.f, 0.f, 0.f};

        short8 afrag[2][2];   // A[m = 16*mt + l][k = 32*ks + quad*8 + j]
        #pragma unroll
        for (int mt = 0; mt < 2; ++mt)
            #pragma unroll
            for (int ks = 0; ks < 2; ++ks)
                afrag[mt][ks] =
                    *reinterpret_cast<const short8*>(&s_xp[(16 * mt + l) * XS + 32 * ks + quad * 8]);

        #pragma unroll
        for (int mt = 0; mt < 2; ++mt)
            #pragma unroll
            for (int nt = 0; nt < 4; ++nt) {
                acc[mt][nt] = __builtin_amdgcn_mfma_f32_16x16x32_bf16(
                    afrag[mt][0], bfrag[nt][0], acc[mt][nt], 0, 0, 0);
                acc[mt][nt] = __builtin_amdgcn_mfma_f32_16x16x32_bf16(
                    afrag[mt][1], bfrag[nt][1], acc[mt][nt], 0, 0, 0);
            }

        // C/D layout: element (reg r, lane) = Out[16*mt + quad*4 + r][16*nt + l]
        if (w < 2) {
            // Q,K: row-major [tok][e] (consumed as contiguous-k fragments in phase 2)
            unsigned short* __restrict__ dst = (w == 0) ? s_q : s_k;
            #pragma unroll
            for (int mt = 0; mt < 2; ++mt)
                #pragma unroll
                for (int nt = 0; nt < 4; ++nt)
                    #pragma unroll
                    for (int r = 0; r < 4; ++r)
                        dst[(16 * mt + quad * 4 + r) * QS + 16 * nt + l] = f2bf(acc[mt][nt][r]);
        } else {
            // V,R: transposed [e][tok] -> r is contiguous -> packed 8B writes (8 vs 32 DS ops)
            unsigned short* __restrict__ dstT = (w == 2) ? s_vt : s_rt;
            #pragma unroll
            for (int mt = 0; mt < 2; ++mt)
                #pragma unroll
                for (int nt = 0; nt < 4; ++nt) {
                    ushort4v pk = { f2bf(acc[mt][nt][0]), f2bf(acc[mt][nt][1]),
                                    f2bf(acc[mt][nt][2]), f2bf(acc[mt][nt][3]) };
                    *reinterpret_cast<ushort4v*>(
                        &dstT[(16 * nt + l) * VS + 16 * mt + 4 * quad]) = pk;
                }
        }
    }
    __syncthreads();

    // ---- phase 2: scores + in-register softmax. wave -> (head h, row-block mt) ----
    const int h  = w >> 1;
    const int mt = w & 1;
    float inv[4];
    {
        const short8 qa =
            *reinterpret_cast<const short8*>(&s_q[(16 * mt + l) * QS + 32 * h + quad * 8]);
        const short8 kb0 =
            *reinterpret_cast<const short8*>(&s_k[(l) * QS + 32 * h + quad * 8]);
        const short8 kb1 =
            *reinterpret_cast<const short8*>(&s_k[(16 + l) * QS + 32 * h + quad * 8]);

        float4v s0 = (float4v){0.f, 0.f, 0.f, 0.f};
        float4v s1 = (float4v){0.f, 0.f, 0.f, 0.f};
        s0 = __builtin_amdgcn_mfma_f32_16x16x32_bf16(qa, kb0, s0, 0, 0, 0);
        s1 = __builtin_amdgcn_mfma_f32_16x16x32_bf16(qa, kb1, s1, 0, 0, 0);

        // row (16*mt + quad*4 + r): its 32 scores live in this quad's 16 lanes x {s0,s1}
        #pragma unroll
        for (int r = 0; r < 4; ++r) {
            float m = fmaxf(s0[r], s1[r]);
            #pragma unroll
            for (int d = 1; d < 16; d <<= 1) m = fmaxf(m, __shfl_xor(m, d));
            const float e0 = __expf(s0[r] - m);
            const float e1 = __expf(s1[r] - m);
            float sum = e0 + e1;
            #pragma unroll
            for (int d = 1; d < 16; d <<= 1) sum += __shfl_xor(sum, d);
            inv[r] = __builtin_amdgcn_rcpf(sum);   // 1-ulp rcp; normalization after PV
            const int row = 16 * mt + quad * 4 + r;
            s_xp[(h * kF + row) * PS + l]      = f2bf(e0);
            s_xp[(h * kF + row) * PS + 16 + l] = f2bf(e1);
        }
    }
    // NO __syncthreads() here: phase 3 reads only P rows written by this same wave
    // (rows h*32+16*mt .. +15); s_vt/s_rt were written before the phase-1 barrier.

    // ---- phase 3: O_h = P_h @ V_h, + residual, relu, store ----
    {
        const short8 pa =
            *reinterpret_cast<const short8*>(&s_xp[(h * kF + 16 * mt + l) * PS + quad * 8]);
        const short8 vb0 =
            *reinterpret_cast<const short8*>(&s_vt[(32 * h + l) * VS + quad * 8]);
        const short8 vb1 =
            *reinterpret_cast<const short8*>(&s_vt[(32 * h + 16 + l) * VS + quad * 8]);

        float4v o0 = (float4v){0.f, 0.f, 0.f, 0.f};
        float4v o1 = (float4v){0.f, 0.f, 0.f, 0.f};
        o0 = __builtin_amdgcn_mfma_f32_16x16x32_bf16(pa, vb0, o0, 0, 0, 0);
        o1 = __builtin_amdgcn_mfma_f32_16x16x32_bf16(pa, vb1, o1, 0, 0, 0);

        // residual: Rt[e][tok] -> r contiguous -> 2 packed 8B reads (was 8 scalar u16)
        const ushort4v rA =
            *reinterpret_cast<const ushort4v*>(&s_rt[(32 * h + l) * VS + 16 * mt + 4 * quad]);
        const ushort4v rB =
            *reinterpret_cast<const ushort4v*>(&s_rt[(32 * h + 16 + l) * VS + 16 * mt + 4 * quad]);

        float* __restrict__ Ob = out + (size_t)b * (kF * kH);
        #pragma unroll
        for (int r = 0; r < 4; ++r) {
            const int f = 16 * mt + quad * 4 + r;
            Ob[f * kH + 32 * h + l]      = fmaxf(o0[r] * inv[r] + bf2f(rA[r]), 0.0f);
            Ob[f * kH + 32 * h + 16 + l] = fmaxf(o1[r] * inv[r] + bf2f(rB[r]), 0.0f);
        }
    }
}

extern "C" void kernel_launch(void* const* d_in, const int* in_sizes, int n_in,
                              void* d_out, int out_size, void* d_ws, size_t ws_size,
                              hipStream_t stream) {
    const float* X  = (const float*)d_in[0];
    const float* Wq = (const float*)d_in[1];
    const float* Wk = (const float*)d_in[2];
    const float* Wv = (const float*)d_in[3];
    const float* Wr = (const float*)d_in[4];
    float* out = (float*)d_out;
    unsigned short* wt = (unsigned short*)d_ws;   // 4*64*64*2 = 32 KiB

    wprep_kernel<<<4, 256, 0, stream>>>(Wq, Wk, Wv, Wr, wt);

    const int B = in_sizes[0] / (kF * kD);        // 16384
    interact_mfma<<<B, 256, 0, stream>>>(X, wt, out);
}